// Round 1
// baseline (225.599 us; speedup 1.0000x reference)
//
#include <hip/hip_runtime.h>
#include <math.h>

#define NROWS 8192
#define NCOLS 4096
#define EPS 1e-8f

// All scratch in device globals: no ws_size dependence, graph-capture safe.
__device__ float g_mask[NROWS];            // 1.0 if label==0 else 0.0
__device__ float g_S[NCOLS];               // masked column sums
__device__ float g_partials[256 * NCOLS];  // per-block column partial sums (4 MB)
__device__ float g_abs[NROWS];             // |cos| per row
__device__ float g_scalars[4];             // 0:n0 1:n1 2:msq(atomic) 3:unused

// ---------- Kernel A: mask + counts + zero msq (1 block x 1024) ----------
__global__ __launch_bounds__(1024) void k_mask(const float* __restrict__ labels) {
    int t = threadIdx.x;
    int cnt = 0;
    #pragma unroll
    for (int j = 0; j < 8; ++j) {
        int r = t + j * 1024;
        float l0 = labels[2 * r];
        float l1 = labels[2 * r + 1];
        bool m0 = (l0 >= l1);            // argmax ties -> index 0
        g_mask[r] = m0 ? 1.f : 0.f;
        cnt += m0 ? 1 : 0;
    }
    // 64-lane wave reduce
    for (int off = 32; off; off >>= 1) cnt += __shfl_xor(cnt, off);
    __shared__ int sh[16];
    int lane = t & 63, w = t >> 6;
    if (lane == 0) sh[w] = cnt;
    __syncthreads();
    if (t == 0) {
        int tot = 0;
        #pragma unroll
        for (int i = 0; i < 16; ++i) tot += sh[i];
        g_scalars[0] = (float)tot;            // n0
        g_scalars[1] = (float)(NROWS - tot);  // n1
        g_scalars[2] = 0.f;                   // msq accumulator
    }
}

// ---------- Kernel B: masked column partial sums (256 blocks x 1024) ----------
// Each block covers 32 rows, all 4096 cols (1024 threads x float4).
__global__ __launch_bounds__(1024) void k_colsum(const float* __restrict__ datas) {
    int b = blockIdx.x, t = threadIdx.x;
    const float4* d4 = (const float4*)datas;
    float4 acc = {0.f, 0.f, 0.f, 0.f};
    int r0 = b * 32;
    #pragma unroll 4
    for (int r = 0; r < 32; ++r) {
        float m = g_mask[r0 + r];  // uniform across block
        float4 v = d4[(size_t)(r0 + r) * (NCOLS / 4) + t];
        acc.x += m * v.x; acc.y += m * v.y; acc.z += m * v.z; acc.w += m * v.w;
    }
    ((float4*)g_partials)[(size_t)b * (NCOLS / 4) + t] = acc;
}

// ---------- Kernel B2: reduce partials -> S, msq (16 blocks x 1024) ----------
__global__ __launch_bounds__(1024) void k_reduceS() {
    int t = threadIdx.x;
    int cl = t & 255;                 // column within block's 256-col slice
    int sub = t >> 8;                 // 0..3: which quarter of the 256 partials
    int c = blockIdx.x * 256 + cl;
    float s = 0.f;
    #pragma unroll 8
    for (int j = 0; j < 64; ++j)
        s += g_partials[(size_t)(sub * 64 + j) * NCOLS + c];
    __shared__ float sh[1024];
    sh[t] = s;
    __syncthreads();
    __shared__ float sh2[256];
    if (t < 256) {
        float tot = sh[t] + sh[t + 256] + sh[t + 512] + sh[t + 768];
        g_S[blockIdx.x * 256 + t] = tot;
        sh2[t] = tot * tot;
    }
    __syncthreads();
    if (t == 0) {
        float m = 0.f;
        #pragma unroll
        for (int i = 0; i < 256; ++i) m += sh2[i];
        atomicAdd(&g_scalars[2], m);  // only 16 atomics total
    }
}

// ---------- Kernel C: per-row dot & norm -> |cos| (1024 blocks x 256) ----------
// One wave (64 lanes) per row; each wave handles 2 rows.
__global__ __launch_bounds__(256) void k_cos(const float* __restrict__ datas) {
    int t = threadIdx.x;
    int lane = t & 63;
    int wv = (blockIdx.x << 2) + (t >> 6);  // global wave id 0..4095
    const float4* d4 = (const float4*)datas;
    const float4* s4 = (const float4*)g_S;
    float n0 = g_scalars[0];
    float n0d = fmaxf(n0, 1.f);
    float msq = g_scalars[2];
    float mnorm = fmaxf(sqrtf(msq) / n0d, EPS);
    #pragma unroll
    for (int rr = 0; rr < 2; ++rr) {
        int r = wv + rr * 4096;
        size_t base = (size_t)r * (NCOLS / 4);
        float dot = 0.f, sq = 0.f;
        #pragma unroll 8
        for (int k = 0; k < 16; ++k) {
            float4 v = d4[base + lane + (k << 6)];
            float4 w = s4[lane + (k << 6)];
            dot += v.x * w.x + v.y * w.y + v.z * w.z + v.w * w.w;
            sq  += v.x * v.x + v.y * v.y + v.z * v.z + v.w * v.w;
        }
        for (int off = 32; off; off >>= 1) {
            dot += __shfl_xor(dot, off);
            sq  += __shfl_xor(sq, off);
        }
        if (lane == 0) {
            float xn = fmaxf(sqrtf(sq), EPS);
            float cosv = (dot / n0d) / (xn * mnorm);
            g_abs[r] = fabsf(cosv);
        }
    }
}

// ---------- Kernel D: final reduction -> 3 outputs (1 block x 1024) ----------
__global__ __launch_bounds__(1024) void k_final(float* __restrict__ out) {
    int t = threadIdx.x;
    float sim = 0.f, dif = 0.f;
    #pragma unroll
    for (int j = 0; j < 8; ++j) {
        int r = t + j * 1024;
        float m = g_mask[r];
        float a = g_abs[r];
        sim += m * (1.f - a);
        dif += (1.f - m) * a;
    }
    for (int off = 32; off; off >>= 1) {
        sim += __shfl_xor(sim, off);
        dif += __shfl_xor(dif, off);
    }
    __shared__ float sh[32];
    int lane = t & 63, w = t >> 6;
    if (lane == 0) { sh[w] = sim; sh[w + 16] = dif; }
    __syncthreads();
    if (t == 0) {
        float s = 0.f, d = 0.f;
        #pragma unroll
        for (int i = 0; i < 16; ++i) { s += sh[i]; d += sh[i + 16]; }
        float n0 = g_scalars[0], n1 = g_scalars[1];
        float simL = (n0 > 0.f) ? s / fmaxf(n0, 1.f) : 0.f;
        float difL = (n0 > 0.f && n1 > 0.f) ? d / fmaxf(n1, 1.f) : 0.f;
        out[0] = simL + difL;
        out[1] = simL;
        out[2] = difL;
    }
}

extern "C" void kernel_launch(void* const* d_in, const int* in_sizes, int n_in,
                              void* d_out, int out_size, void* d_ws, size_t ws_size,
                              hipStream_t stream) {
    const float* labels = (const float*)d_in[0];
    const float* datas  = (const float*)d_in[1];
    float* out = (float*)d_out;

    k_mask<<<1, 1024, 0, stream>>>(labels);
    k_colsum<<<256, 1024, 0, stream>>>(datas);
    k_reduceS<<<16, 1024, 0, stream>>>();
    k_cos<<<1024, 256, 0, stream>>>(datas);
    k_final<<<1, 1024, 0, stream>>>(out);
}